// Round 1
// baseline (564.422 us; speedup 1.0000x reference)
//
#include <hip/hip_runtime.h>
#include <hip/hip_bf16.h>
#include <stdint.h>

// Problem constants
#define INPUT_SIZE   736
#define PLANE_ELEMS  (736*736)        // 541696
#define N_RINGS      368
#define PATCH_LEN    768
#define EMBED        768
#define BATCH        32
#define KDIM         768              // 3*16*16
#define M_TOTAL      (BATCH*23*48)    // 35328 = 276*128
#define P_PER_BATCH  1104             // 23*48
#define OUT_BATCH_STRIDE 847872       // 768*1104

typedef __bf16 bf16x8 __attribute__((ext_vector_type(8)));
typedef float  floatx4 __attribute__((ext_vector_type(4)));

// ---------------------------------------------------------------------------
// Kernel 1: cast conv_w (fp32, [E=768][K=768] flat) -> bf16 Wb
// ---------------------------------------------------------------------------
__global__ void wcast_kernel(const float* __restrict__ wsrc,
                             __hip_bfloat16* __restrict__ Wb) {
    int i = blockIdx.x * 256 + threadIdx.x;   // grid covers 589824 exactly
    Wb[i] = __float2bfloat16(wsrc[i]);
}

// ---------------------------------------------------------------------------
// Kernel 2: gather + lerp -> A[m][k] bf16 (GEMM A operand, K-contiguous)
//   m = n*1104 + ph*48 + pw ; k = c*256 + py*16 + px
//   patches[n][c][r=16ph+py][j=16pw+px]
// One block per (n,c,r): 256 threads, 3 j-elements each.
// ---------------------------------------------------------------------------
__global__ void gather_kernel(const float* __restrict__ x,
                              const int*   __restrict__ idx0,
                              const int*   __restrict__ idx1,
                              const float* __restrict__ w,
                              __hip_bfloat16* __restrict__ A) {
    int b  = blockIdx.x;            // (n*3+c)*368 + r
    int r  = b % N_RINGS;
    int nc = b / N_RINGS;           // n*3+c
    int c  = nc % 3;
    int n  = nc / 3;
    const float* plane = x + (size_t)nc * PLANE_ELEMS;
    int rowbase = r * PATCH_LEN;
    int m_base  = n * P_PER_BATCH + (r >> 4) * 48;
    int k_base  = c * 256 + (r & 15) * 16;
    #pragma unroll
    for (int it = 0; it < 3; it++) {
        int jj = threadIdx.x + it * 256;
        int t  = rowbase + jj;
        int i0 = idx0[t];
        int i1 = idx1[t];
        float wt = w[t];
        float v  = plane[i0] * (1.0f - wt) + plane[i1] * wt;
        int m = m_base + (jj >> 4);
        int k = k_base + (jj & 15);
        A[(size_t)m * KDIM + k] = __float2bfloat16(v);
    }
}

// ---------------------------------------------------------------------------
// Kernel 3: GEMM  C[m][e] = sum_k A[m][k] * Wb[e][k]  + bias[e]
//   M=35328 (276 tiles), E=768 (6 tiles), K=768 (24 x BK=32)
//   128x128 tile, 4 waves, each wave = 64x64 via 4x4 grid of 16x16x32 MFMA.
//   Staging: global_load_lds dwordx4 (m97 pattern).
//   Epilogue: LDS transpose (stride 17) -> coalesced 256B store runs along p.
// ---------------------------------------------------------------------------
__global__ __launch_bounds__(256) void gemm_kernel(
        const __hip_bfloat16* __restrict__ A,   // [35328][768]
        const __hip_bfloat16* __restrict__ Wb,  // [768][768] (E,K) = B^T
        const float* __restrict__ cb,           // [768]
        float* __restrict__ out)                // [32][768][1104]
{
    __shared__ __hip_bfloat16 As[128 * 32];
    __shared__ __hip_bfloat16 Bs[128 * 32];
    __shared__ float Ep[4][64 * 17];            // per-wave transpose buffer

    const int tid  = threadIdx.x;
    const int lane = tid & 63;
    const int wv   = tid >> 6;
    const int wm   = wv & 1;      // wave row (0..1)
    const int wn   = wv >> 1;     // wave col (0..1)
    const int quad = lane >> 4;
    const int l16  = lane & 15;

    const int bn = blockIdx.x;    // 0..5   (embed tiles)
    const int bm = blockIdx.y;    // 0..275 (m tiles)

    floatx4 acc[4][4];
    #pragma unroll
    for (int i = 0; i < 4; i++)
        #pragma unroll
        for (int j = 0; j < 4; j++)
            acc[i][j] = (floatx4){0.f, 0.f, 0.f, 0.f};

    // staging addresses: thread t loads 16B = 8 bf16; row = t>>2, kseg=(t&3)*8
    const int srow = tid >> 2;          // 0..63
    const int kofs = (tid & 3) * 8;     // 0,8,16,24
    const __hip_bfloat16* aSrc = A  + (size_t)(bm * 128 + srow) * KDIM + kofs;
    const __hip_bfloat16* bSrc = Wb + (size_t)(bn * 128 + srow) * KDIM + kofs;
    __hip_bfloat16* aDst = As + tid * 8;        // lane*16B within wave region
    __hip_bfloat16* bDst = Bs + tid * 8;

    for (int kt = 0; kt < 24; kt++) {
        const __hip_bfloat16* ap = aSrc + kt * 32;
        const __hip_bfloat16* bp = bSrc + kt * 32;
        __builtin_amdgcn_global_load_lds(
            (const __attribute__((address_space(1))) void*)(const void*)ap,
            (__attribute__((address_space(3))) void*)(void*)aDst, 16, 0, 0);
        __builtin_amdgcn_global_load_lds(
            (const __attribute__((address_space(1))) void*)(const void*)(ap + (size_t)64 * KDIM),
            (__attribute__((address_space(3))) void*)(void*)(aDst + 64 * 32), 16, 0, 0);
        __builtin_amdgcn_global_load_lds(
            (const __attribute__((address_space(1))) void*)(const void*)bp,
            (__attribute__((address_space(3))) void*)(void*)bDst, 16, 0, 0);
        __builtin_amdgcn_global_load_lds(
            (const __attribute__((address_space(1))) void*)(const void*)(bp + (size_t)64 * KDIM),
            (__attribute__((address_space(3))) void*)(void*)(bDst + 64 * 32), 16, 0, 0);
        __syncthreads();   // drains vmcnt + barrier

        bf16x8 af[4], bfr[4];
        #pragma unroll
        for (int mi = 0; mi < 4; mi++) {
            int ml = wm * 64 + mi * 16 + l16;
            af[mi] = *(const bf16x8*)(As + ml * 32 + quad * 8);
        }
        #pragma unroll
        for (int ni = 0; ni < 4; ni++) {
            int el = wn * 64 + ni * 16 + l16;
            bfr[ni] = *(const bf16x8*)(Bs + el * 32 + quad * 8);
        }
        #pragma unroll
        for (int mi = 0; mi < 4; mi++)
            #pragma unroll
            for (int ni = 0; ni < 4; ni++)
                acc[mi][ni] = __builtin_amdgcn_mfma_f32_16x16x32_bf16(
                                  af[mi], bfr[ni], acc[mi][ni], 0, 0, 0);
        __syncthreads();   // protect As/Bs before next staging
    }

    // ---------------- epilogue: transpose through LDS, coalesced stores ----
    float* ep = Ep[wv];
    const int m0 = bm * 128 + wm * 64;
    const int e0 = bn * 128 + wn * 64;

    for (int ni = 0; ni < 4; ni++) {
        #pragma unroll
        for (int mi = 0; mi < 4; mi++)
            #pragma unroll
            for (int r2 = 0; r2 < 4; r2++)
                ep[(mi * 16 + quad * 4 + r2) * 17 + l16] = acc[mi][ni][r2];
        __syncthreads();
        #pragma unroll
        for (int ee = 0; ee < 16; ee++) {
            float v = ep[lane * 17 + ee];
            int eg = e0 + ni * 16 + ee;
            int mg = m0 + lane;
            int nb = mg / P_PER_BATCH;           // magic-mul
            int p  = mg - nb * P_PER_BATCH;
            out[(size_t)nb * OUT_BATCH_STRIDE + (size_t)eg * P_PER_BATCH + p]
                = v + cb[eg];
        }
        __syncthreads();
    }
}

// ---------------------------------------------------------------------------
extern "C" void kernel_launch(void* const* d_in, const int* in_sizes, int n_in,
                              void* d_out, int out_size, void* d_ws, size_t ws_size,
                              hipStream_t stream) {
    const float* x      = (const float*)d_in[0];   // (32,3,736,736)
    const float* conv_w = (const float*)d_in[1];   // (768,3,16,16) = (768,768)
    const float* conv_b = (const float*)d_in[2];   // (768,)
    const int*   idx0   = (const int*)  d_in[3];   // (368*768,)
    const int*   idx1   = (const int*)  d_in[4];
    const float* w      = (const float*)d_in[5];
    float* out = (float*)d_out;

    __hip_bfloat16* A  = (__hip_bfloat16*)d_ws;                 // 54.3 MB
    __hip_bfloat16* Wb = A + (size_t)M_TOTAL * KDIM;            // +1.2 MB

    // 1) weight cast: 589824 elements
    wcast_kernel<<<dim3(EMBED * KDIM / 256), dim3(256), 0, stream>>>(conv_w, Wb);

    // 2) gather+lerp -> A : one block per (n,c,ring)
    gather_kernel<<<dim3(BATCH * 3 * N_RINGS), dim3(256), 0, stream>>>(
        x, idx0, idx1, w, A);

    // 3) GEMM + bias -> out
    gemm_kernel<<<dim3(EMBED / 128, M_TOTAL / 128), dim3(256), 0, stream>>>(
        A, Wb, conv_b, out);
}

// Round 2
// 455.881 us; speedup vs baseline: 1.2381x; 1.2381x over previous
//
#include <hip/hip_runtime.h>
#include <hip/hip_bf16.h>
#include <stdint.h>

// Problem constants
#define INPUT_SIZE   736
#define PLANE_ELEMS  (736*736)        // 541696
#define N_RINGS      368
#define PATCH_LEN    768
#define EMBED        768
#define BATCH        32
#define KDIM         768              // 3*16*16
#define M_TOTAL      (BATCH*23*48)    // 35328 = 276*128
#define P_PER_BATCH  1104             // 23*48
#define OUT_BATCH_STRIDE 847872       // 768*1104

typedef __bf16 bf16x8 __attribute__((ext_vector_type(8)));
typedef float  floatx4 __attribute__((ext_vector_type(4)));

// ---------------------------------------------------------------------------
// Kernel 1: cast conv_w (fp32, [E=768][K=768] flat) -> bf16 Wb
// ---------------------------------------------------------------------------
__global__ void wcast_kernel(const float* __restrict__ wsrc,
                             __hip_bfloat16* __restrict__ Wb) {
    int i = blockIdx.x * 256 + threadIdx.x;   // grid covers 589824 exactly
    Wb[i] = __float2bfloat16(wsrc[i]);
}

// ---------------------------------------------------------------------------
// Kernel 2: gather + lerp -> A[m][k] bf16 (GEMM A operand, K-contiguous)
//   Locality tiling: one block per (n, c, 16-ring band). Threads are
//   (ring rr = tid>>4, angle jj = tid&15); loop jc over 48 angle chunks.
//   Same j across adjacent rings = same angle = spatially adjacent pixels,
//   so each 16x16 (ring x j) step is a compact patch -> cache-line reuse.
//   Writes: m = n*1104 + band*48 + jc (uniform per block per iter),
//           k = c*256 + tid  -> 512 B contiguous per block-iteration.
// ---------------------------------------------------------------------------
__global__ void gather_kernel(const float* __restrict__ x,
                              const int*   __restrict__ idx0,
                              const int*   __restrict__ idx1,
                              const float* __restrict__ w,
                              __hip_bfloat16* __restrict__ A) {
    int b    = blockIdx.x;          // (n*3+c)*23 + band
    int band = b % 23;
    int nc   = b / 23;              // n*3+c
    int c    = nc % 3;
    int n    = nc / 3;
    const float* plane = x + (size_t)nc * PLANE_ELEMS;

    int rr = threadIdx.x >> 4;      // ring within band, 0..15
    int jj = threadIdx.x & 15;      // angle within chunk, 0..15
    int r  = band * 16 + rr;
    int tbase = r * PATCH_LEN + jj;
    size_t abase = ((size_t)(n * P_PER_BATCH + band * 48)) * KDIM
                 + c * 256 + threadIdx.x;

    #pragma unroll 4
    for (int jc = 0; jc < 48; jc++) {
        int t  = tbase + jc * 16;
        int i0 = idx0[t];
        int i1 = idx1[t];
        float wt = w[t];
        float v  = plane[i0] * (1.0f - wt) + plane[i1] * wt;
        A[abase + (size_t)jc * KDIM] = __float2bfloat16(v);
    }
}

// ---------------------------------------------------------------------------
// Kernel 3: GEMM  C[m][e] = sum_k A[m][k] * Wb[e][k]  + bias[e]
//   M=35328 (276 tiles), E=768 (6 tiles), K=768 (24 x BK=32)
//   128x128 tile, 4 waves, each wave = 64x64 via 4x4 grid of 16x16x32 MFMA.
//   Staging: global_load_lds dwordx4 (m97 pattern).
//   Epilogue: direct float4 stores (4 consecutive m per lane from C-layout
//   row=quad*4+reg; 1104 % 4 == 0 so no batch-boundary crossing); L2
//   write-back merges the e-scattered 16B stores into full lines.
// ---------------------------------------------------------------------------
__global__ __launch_bounds__(256) void gemm_kernel(
        const __hip_bfloat16* __restrict__ A,   // [35328][768]
        const __hip_bfloat16* __restrict__ Wb,  // [768][768] (E,K) = B^T
        const float* __restrict__ cb,           // [768]
        float* __restrict__ out)                // [32][768][1104]
{
    __shared__ __hip_bfloat16 As[128 * 32];
    __shared__ __hip_bfloat16 Bs[128 * 32];

    const int tid  = threadIdx.x;
    const int lane = tid & 63;
    const int wv   = tid >> 6;
    const int wm   = wv & 1;      // wave row (0..1)
    const int wn   = wv >> 1;     // wave col (0..1)
    const int quad = lane >> 4;
    const int l16  = lane & 15;

    const int bn = blockIdx.x;    // 0..5   (embed tiles)
    const int bm = blockIdx.y;    // 0..275 (m tiles)

    floatx4 acc[4][4];
    #pragma unroll
    for (int i = 0; i < 4; i++)
        #pragma unroll
        for (int j = 0; j < 4; j++)
            acc[i][j] = (floatx4){0.f, 0.f, 0.f, 0.f};

    // staging addresses: thread t loads 16B = 8 bf16; row = t>>2, kseg=(t&3)*8
    const int srow = tid >> 2;          // 0..63
    const int kofs = (tid & 3) * 8;     // 0,8,16,24
    const __hip_bfloat16* aSrc = A  + (size_t)(bm * 128 + srow) * KDIM + kofs;
    const __hip_bfloat16* bSrc = Wb + (size_t)(bn * 128 + srow) * KDIM + kofs;
    __hip_bfloat16* aDst = As + tid * 8;        // lane*16B within wave region
    __hip_bfloat16* bDst = Bs + tid * 8;

    for (int kt = 0; kt < 24; kt++) {
        const __hip_bfloat16* ap = aSrc + kt * 32;
        const __hip_bfloat16* bp = bSrc + kt * 32;
        __builtin_amdgcn_global_load_lds(
            (const __attribute__((address_space(1))) void*)(const void*)ap,
            (__attribute__((address_space(3))) void*)(void*)aDst, 16, 0, 0);
        __builtin_amdgcn_global_load_lds(
            (const __attribute__((address_space(1))) void*)(const void*)(ap + (size_t)64 * KDIM),
            (__attribute__((address_space(3))) void*)(void*)(aDst + 64 * 32), 16, 0, 0);
        __builtin_amdgcn_global_load_lds(
            (const __attribute__((address_space(1))) void*)(const void*)bp,
            (__attribute__((address_space(3))) void*)(void*)bDst, 16, 0, 0);
        __builtin_amdgcn_global_load_lds(
            (const __attribute__((address_space(1))) void*)(const void*)(bp + (size_t)64 * KDIM),
            (__attribute__((address_space(3))) void*)(void*)(bDst + 64 * 32), 16, 0, 0);
        __syncthreads();   // drains vmcnt + barrier

        bf16x8 af[4], bfr[4];
        #pragma unroll
        for (int mi = 0; mi < 4; mi++) {
            int ml = wm * 64 + mi * 16 + l16;
            af[mi] = *(const bf16x8*)(As + ml * 32 + quad * 8);
        }
        #pragma unroll
        for (int ni = 0; ni < 4; ni++) {
            int el = wn * 64 + ni * 16 + l16;
            bfr[ni] = *(const bf16x8*)(Bs + el * 32 + quad * 8);
        }
        #pragma unroll
        for (int mi = 0; mi < 4; mi++)
            #pragma unroll
            for (int ni = 0; ni < 4; ni++)
                acc[mi][ni] = __builtin_amdgcn_mfma_f32_16x16x32_bf16(
                                  af[mi], bfr[ni], acc[mi][ni], 0, 0, 0);
        __syncthreads();   // protect As/Bs before next staging
    }

    // ---------------- epilogue: direct float4 stores ----------------------
    const int m0 = bm * 128 + wm * 64;
    const int e0 = bn * 128 + wn * 64;
    #pragma unroll
    for (int ni = 0; ni < 4; ni++) {
        int eg = e0 + ni * 16 + l16;
        float bias = cb[eg];
        #pragma unroll
        for (int mi = 0; mi < 4; mi++) {
            int mg = m0 + mi * 16 + quad * 4;
            int nb = mg / P_PER_BATCH;          // magic-mul
            int p  = mg - nb * P_PER_BATCH;
            floatx4 v = acc[mi][ni];
            v[0] += bias; v[1] += bias; v[2] += bias; v[3] += bias;
            *(floatx4*)(out + (size_t)nb * OUT_BATCH_STRIDE
                            + (size_t)eg * P_PER_BATCH + p) = v;
        }
    }
}

// ---------------------------------------------------------------------------
extern "C" void kernel_launch(void* const* d_in, const int* in_sizes, int n_in,
                              void* d_out, int out_size, void* d_ws, size_t ws_size,
                              hipStream_t stream) {
    const float* x      = (const float*)d_in[0];   // (32,3,736,736)
    const float* conv_w = (const float*)d_in[1];   // (768,3,16,16) = (768,768)
    const float* conv_b = (const float*)d_in[2];   // (768,)
    const int*   idx0   = (const int*)  d_in[3];   // (368*768,)
    const int*   idx1   = (const int*)  d_in[4];
    const float* w      = (const float*)d_in[5];
    float* out = (float*)d_out;

    __hip_bfloat16* A  = (__hip_bfloat16*)d_ws;                 // 54.3 MB
    __hip_bfloat16* Wb = A + (size_t)M_TOTAL * KDIM;            // +1.2 MB

    // 1) weight cast: 589824 elements
    wcast_kernel<<<dim3(EMBED * KDIM / 256), dim3(256), 0, stream>>>(conv_w, Wb);

    // 2) gather+lerp -> A : one block per (n, c, 16-ring band)
    gather_kernel<<<dim3(BATCH * 3 * (N_RINGS / 16)), dim3(256), 0, stream>>>(
        x, idx0, idx1, w, A);

    // 3) GEMM + bias -> out
    gemm_kernel<<<dim3(EMBED / 128, M_TOTAL / 128), dim3(256), 0, stream>>>(
        A, Wb, conv_b, out);
}

// Round 3
// 442.852 us; speedup vs baseline: 1.2745x; 1.0294x over previous
//
#include <hip/hip_runtime.h>
#include <hip/hip_bf16.h>
#include <stdint.h>

// Problem constants
#define INPUT_SIZE   736
#define PLANE_ELEMS  (736*736)        // 541696
#define N_RINGS      368
#define PATCH_LEN    768
#define EMBED        768
#define BATCH        32
#define KDIM         768              // 3*16*16
#define M_TOTAL      (BATCH*23*48)    // 35328 = 276*128
#define P_PER_BATCH  1104             // 23*48
#define OUT_BATCH_STRIDE 847872       // 768*1104

typedef __bf16 bf16x8 __attribute__((ext_vector_type(8)));
typedef float  floatx4 __attribute__((ext_vector_type(4)));

// ---------------------------------------------------------------------------
// Kernel 1: cast conv_w (fp32, [E=768][K=768] flat) -> bf16 Wb
// ---------------------------------------------------------------------------
__global__ void wcast_kernel(const float* __restrict__ wsrc,
                             __hip_bfloat16* __restrict__ Wb) {
    int i = blockIdx.x * 256 + threadIdx.x;   // grid covers 589824 exactly
    Wb[i] = __float2bfloat16(wsrc[i]);
}

// ---------------------------------------------------------------------------
// Kernel 2: gather + lerp -> A[m][k] bf16 (GEMM A operand, K-contiguous)
//   Locality tiling: one block per (n, c, band, half). Threads are
//   (ring rr = tid>>4, angle jj = tid&15); loop jc over 24 angle chunks.
//   R2->R3: grid 2208->4416 blocks (half the per-thread serial chain, less
//   tail imbalance) + unroll 8 (deeper gather MLP: ~16 outstanding scattered
//   loads/wave). Gather was latency-bound at 2.45 TB/s, VALUBusy 6%.
//   Writes: k = c*256 + tid -> 512 B contiguous per block-iteration.
// ---------------------------------------------------------------------------
__global__ void gather_kernel(const float* __restrict__ x,
                              const int*   __restrict__ idx0,
                              const int*   __restrict__ idx1,
                              const float* __restrict__ w,
                              __hip_bfloat16* __restrict__ A) {
    int b    = blockIdx.x;          // ((n*3+c)*23 + band)*2 + half
    int half = b & 1;
    int bb   = b >> 1;
    int band = bb % 23;
    int nc   = bb / 23;             // n*3+c
    int c    = nc % 3;
    int n    = nc / 3;
    const float* plane = x + (size_t)nc * PLANE_ELEMS;

    int rr = threadIdx.x >> 4;      // ring within band, 0..15
    int jj = threadIdx.x & 15;      // angle within chunk, 0..15
    int r  = band * 16 + rr;
    int tbase = r * PATCH_LEN + jj + half * (24 * 16);
    size_t abase = ((size_t)(n * P_PER_BATCH + band * 48 + half * 24)) * KDIM
                 + c * 256 + threadIdx.x;

    #pragma unroll 8
    for (int jc = 0; jc < 24; jc++) {
        int t  = tbase + jc * 16;
        int i0 = idx0[t];
        int i1 = idx1[t];
        float wt = w[t];
        float v  = plane[i0] * (1.0f - wt) + plane[i1] * wt;
        A[abase + (size_t)jc * KDIM] = __float2bfloat16(v);
    }
}

// ---------------------------------------------------------------------------
// Kernel 3: GEMM  C[m][e] = sum_k A[m][k] * Wb[e][k]  + bias[e]
//   M=35328 (276 tiles), E=768 (6 tiles), K=768 (24 x BK=32)
//   128x128 tile, 4 waves, each wave = 64x64 via 4x4 grid of 16x16x32 MFMA.
//   Staging: global_load_lds dwordx4 (m97 pattern).
//   Epilogue: direct float4 stores (4 consecutive m per lane from C-layout
//   row=quad*4+reg; 1104 % 4 == 0 so no batch-boundary crossing); L2
//   write-back merges the e-scattered 16B stores into full lines.
// ---------------------------------------------------------------------------
__global__ __launch_bounds__(256) void gemm_kernel(
        const __hip_bfloat16* __restrict__ A,   // [35328][768]
        const __hip_bfloat16* __restrict__ Wb,  // [768][768] (E,K) = B^T
        const float* __restrict__ cb,           // [768]
        float* __restrict__ out)                // [32][768][1104]
{
    __shared__ __hip_bfloat16 As[128 * 32];
    __shared__ __hip_bfloat16 Bs[128 * 32];

    const int tid  = threadIdx.x;
    const int lane = tid & 63;
    const int wv   = tid >> 6;
    const int wm   = wv & 1;      // wave row (0..1)
    const int wn   = wv >> 1;     // wave col (0..1)
    const int quad = lane >> 4;
    const int l16  = lane & 15;

    const int bn = blockIdx.x;    // 0..5   (embed tiles)
    const int bm = blockIdx.y;    // 0..275 (m tiles)

    floatx4 acc[4][4];
    #pragma unroll
    for (int i = 0; i < 4; i++)
        #pragma unroll
        for (int j = 0; j < 4; j++)
            acc[i][j] = (floatx4){0.f, 0.f, 0.f, 0.f};

    // staging addresses: thread t loads 16B = 8 bf16; row = t>>2, kseg=(t&3)*8
    const int srow = tid >> 2;          // 0..63
    const int kofs = (tid & 3) * 8;     // 0,8,16,24
    const __hip_bfloat16* aSrc = A  + (size_t)(bm * 128 + srow) * KDIM + kofs;
    const __hip_bfloat16* bSrc = Wb + (size_t)(bn * 128 + srow) * KDIM + kofs;
    __hip_bfloat16* aDst = As + tid * 8;        // lane*16B within wave region
    __hip_bfloat16* bDst = Bs + tid * 8;

    for (int kt = 0; kt < 24; kt++) {
        const __hip_bfloat16* ap = aSrc + kt * 32;
        const __hip_bfloat16* bp = bSrc + kt * 32;
        __builtin_amdgcn_global_load_lds(
            (const __attribute__((address_space(1))) void*)(const void*)ap,
            (__attribute__((address_space(3))) void*)(void*)aDst, 16, 0, 0);
        __builtin_amdgcn_global_load_lds(
            (const __attribute__((address_space(1))) void*)(const void*)(ap + (size_t)64 * KDIM),
            (__attribute__((address_space(3))) void*)(void*)(aDst + 64 * 32), 16, 0, 0);
        __builtin_amdgcn_global_load_lds(
            (const __attribute__((address_space(1))) void*)(const void*)bp,
            (__attribute__((address_space(3))) void*)(void*)bDst, 16, 0, 0);
        __builtin_amdgcn_global_load_lds(
            (const __attribute__((address_space(1))) void*)(const void*)(bp + (size_t)64 * KDIM),
            (__attribute__((address_space(3))) void*)(void*)(bDst + 64 * 32), 16, 0, 0);
        __syncthreads();   // drains vmcnt + barrier

        bf16x8 af[4], bfr[4];
        #pragma unroll
        for (int mi = 0; mi < 4; mi++) {
            int ml = wm * 64 + mi * 16 + l16;
            af[mi] = *(const bf16x8*)(As + ml * 32 + quad * 8);
        }
        #pragma unroll
        for (int ni = 0; ni < 4; ni++) {
            int el = wn * 64 + ni * 16 + l16;
            bfr[ni] = *(const bf16x8*)(Bs + el * 32 + quad * 8);
        }
        #pragma unroll
        for (int mi = 0; mi < 4; mi++)
            #pragma unroll
            for (int ni = 0; ni < 4; ni++)
                acc[mi][ni] = __builtin_amdgcn_mfma_f32_16x16x32_bf16(
                                  af[mi], bfr[ni], acc[mi][ni], 0, 0, 0);
        __syncthreads();   // protect As/Bs before next staging
    }

    // ---------------- epilogue: direct float4 stores ----------------------
    const int m0 = bm * 128 + wm * 64;
    const int e0 = bn * 128 + wn * 64;
    #pragma unroll
    for (int ni = 0; ni < 4; ni++) {
        int eg = e0 + ni * 16 + l16;
        float bias = cb[eg];
        #pragma unroll
        for (int mi = 0; mi < 4; mi++) {
            int mg = m0 + mi * 16 + quad * 4;
            int nb = mg / P_PER_BATCH;          // magic-mul
            int p  = mg - nb * P_PER_BATCH;
            floatx4 v = acc[mi][ni];
            v[0] += bias; v[1] += bias; v[2] += bias; v[3] += bias;
            *(floatx4*)(out + (size_t)nb * OUT_BATCH_STRIDE
                            + (size_t)eg * P_PER_BATCH + p) = v;
        }
    }
}

// ---------------------------------------------------------------------------
extern "C" void kernel_launch(void* const* d_in, const int* in_sizes, int n_in,
                              void* d_out, int out_size, void* d_ws, size_t ws_size,
                              hipStream_t stream) {
    const float* x      = (const float*)d_in[0];   // (32,3,736,736)
    const float* conv_w = (const float*)d_in[1];   // (768,3,16,16) = (768,768)
    const float* conv_b = (const float*)d_in[2];   // (768,)
    const int*   idx0   = (const int*)  d_in[3];   // (368*768,)
    const int*   idx1   = (const int*)  d_in[4];
    const float* w      = (const float*)d_in[5];
    float* out = (float*)d_out;

    __hip_bfloat16* A  = (__hip_bfloat16*)d_ws;                 // 54.3 MB
    __hip_bfloat16* Wb = A + (size_t)M_TOTAL * KDIM;            // +1.2 MB

    // 1) weight cast: 589824 elements
    wcast_kernel<<<dim3(EMBED * KDIM / 256), dim3(256), 0, stream>>>(conv_w, Wb);

    // 2) gather+lerp -> A : one block per (n, c, band, half)
    gather_kernel<<<dim3(BATCH * 3 * (N_RINGS / 16) * 2), dim3(256), 0, stream>>>(
        x, idx0, idx1, w, A);

    // 3) GEMM + bias -> out
    gemm_kernel<<<dim3(EMBED / 128, M_TOTAL / 128), dim3(256), 0, stream>>>(
        A, Wb, conv_b, out);
}